// Round 1
// baseline (174.016 us; speedup 1.0000x reference)
//
#include <hip/hip_runtime.h>
#include <math.h>

#define NHID 1024
#define NIN 14
#define NKEYS 100000
#define NRD 10
#define NB1 391          // ceil(100000/256)
#define R3 100           // rows per block in k3; 1000 * 100 = 100000 exactly
#define NB3 1000

// ws float-index layout (total ~9216 floats = 36 KB)
#define WS_BLOCKML 0     // 2*NB1 = 782
#define WS_ML      800   // M, invL
#define WS_MACC    1024  // 1024 floats, 16B aligned
#define WS_PREACT  2048  // 5120
#define WS_HH      7168  // 1024
#define WS_HT      8192  // 1024

__device__ inline float wave_reduce_sum(float v) {
#pragma unroll
    for (int off = 32; off > 0; off >>= 1) v += __shfl_down(v, off, 64);
    return v;
}

__device__ inline float sigm(float x) { return 1.0f / (1.0f + expf(-x)); }

// load q (clamped dynamic_slice like JAX) and its norm
__device__ inline float load_q(const float* __restrict__ x, int pick, float* q) {
    int start = pick * NRD;
    if (start > NIN - NRD) start = NIN - NRD;
    if (start < 0) start = 0;
    float qn = 0.f;
#pragma unroll
    for (int k = 0; k < NRD; ++k) { q[k] = x[start + k]; qn = fmaf(q[k], q[k], qn); }
    return sqrtf(qn);
}

__device__ inline float score_for(const float* __restrict__ keys, int i,
                                  const float* q, float qn) {
    float dot = 0.f, kn = 0.f;
#pragma unroll
    for (int k = 0; k < NRD; ++k) {
        float kv = keys[(size_t)i * NRD + k];
        dot = fmaf(kv, q[k], dot);
        kn = fmaf(kv, kv, kn);
    }
    return dot / fmaxf(sqrtf(kn) * qn, 1e-8f);
}

// preact[r] = W_i2h[r,:]·x + b_i2h[r] + W_h2h[r,:]·h + b_h2h[r], r < 5120
__global__ void k_pre(const float* __restrict__ x, const float* __restrict__ h,
                      const float* __restrict__ Wi, const float* __restrict__ bi,
                      const float* __restrict__ Wh, const float* __restrict__ bh,
                      float* __restrict__ preact) {
    int wave = threadIdx.x >> 6, lane = threadIdx.x & 63;
    int row = blockIdx.x * 4 + wave;
    const float4* w4 = (const float4*)(Wh + (size_t)row * NHID);
    const float4* h4 = (const float4*)h;
    float p = 0.f;
#pragma unroll
    for (int j = 0; j < 4; ++j) {
        float4 wv = w4[j * 64 + lane];
        float4 hv = h4[j * 64 + lane];
        p += wv.x * hv.x + wv.y * hv.y + wv.z * hv.z + wv.w * hv.w;
    }
    if (lane < NIN) p += x[lane] * Wi[(size_t)row * NIN + lane];
    p = wave_reduce_sum(p);
    if (lane == 0) preact[row] = p + bi[row] + bh[row];
}

// per-block online softmax stats over scores
__global__ void k1_stats(const float* __restrict__ keys, const float* __restrict__ x,
                         const int* __restrict__ pick_arm, float* __restrict__ blockml) {
    __shared__ float red[256];
    int tid = threadIdx.x;
    int i = blockIdx.x * 256 + tid;
    float q[NRD];
    float qn = load_q(x, pick_arm[0], q);
    float sv = -1e30f;
    if (i < NKEYS) sv = score_for(keys, i, q, qn);
    red[tid] = sv; __syncthreads();
    for (int off = 128; off > 0; off >>= 1) {
        if (tid < off) red[tid] = fmaxf(red[tid], red[tid + off]);
        __syncthreads();
    }
    float mb = red[0]; __syncthreads();
    float e = (i < NKEYS) ? expf(sv - mb) : 0.f;
    red[tid] = e; __syncthreads();
    for (int off = 128; off > 0; off >>= 1) {
        if (tid < off) red[tid] += red[tid + off];
        __syncthreads();
    }
    if (tid == 0) { blockml[2 * blockIdx.x] = mb; blockml[2 * blockIdx.x + 1] = red[0]; }
}

// combine block stats -> M, 1/L ; zero macc
__global__ void k2_combine(const float* __restrict__ blockml, float* __restrict__ ML,
                           float* __restrict__ macc) {
    __shared__ float red[512];
    int t = threadIdx.x;
    float m = (t < NB1) ? blockml[2 * t] : -1e30f;
    float l = (t < NB1) ? blockml[2 * t + 1] : 0.f;
    red[t] = m; __syncthreads();
    for (int off = 256; off > 0; off >>= 1) {
        if (t < off) red[t] = fmaxf(red[t], red[t + off]);
        __syncthreads();
    }
    float M = red[0]; __syncthreads();
    red[t] = l * expf(m - M); __syncthreads();
    for (int off = 256; off > 0; off >>= 1) {
        if (t < off) red[t] += red[t + off];
        __syncthreads();
    }
    if (t == 0) { ML[0] = M; ML[1] = 1.0f / red[0]; }
    macc[t] = 0.f;
    macc[t + 512] = 0.f;
}

// the big weighted reduction over vals
__global__ void __launch_bounds__(256) k3_pv(const float* __restrict__ keys,
                                             const float* __restrict__ x,
                                             const int* __restrict__ pick_arm,
                                             const float* __restrict__ ML,
                                             const float* __restrict__ vals,
                                             float* __restrict__ macc) {
    __shared__ float wl[R3];
    int tid = threadIdx.x;
    int r0 = blockIdx.x * R3;
    float M = ML[0], invL = ML[1];
    if (tid < R3) {
        float q[NRD];
        float qn = load_q(x, pick_arm[0], q);
        float sv = score_for(keys, r0 + tid, q, qn);
        wl[tid] = expf(sv - M) * invL;
    }
    __syncthreads();
    const float4* vp = (const float4*)vals + ((size_t)r0 << 8) + tid;
    float4 acc = make_float4(0.f, 0.f, 0.f, 0.f);
#pragma unroll 4
    for (int r = 0; r < R3; ++r) {
        float w = wl[r];
        float4 v = vp[(size_t)r << 8];
        acc.x = fmaf(w, v.x, acc.x);
        acc.y = fmaf(w, v.y, acc.y);
        acc.z = fmaf(w, v.z, acc.z);
        acc.w = fmaf(w, v.w, acc.w);
    }
    atomicAdd(&macc[4 * tid + 0], acc.x);
    atomicAdd(&macc[4 * tid + 1], acc.y);
    atomicAdd(&macc[4 * tid + 2], acc.z);
    atomicAdd(&macc[4 * tid + 3], acc.w);
}

// gates + cell update; write h_t, c_t to out and h_t to ws
__global__ void k4_cell(const float* __restrict__ preact, const float* __restrict__ macc,
                        const float* __restrict__ c_in, float* __restrict__ out,
                        float* __restrict__ ht_ws) {
    int t = blockIdx.x * 256 + threadIdx.x;
    float f = sigm(preact[t]);
    float i = sigm(preact[NHID + t]);
    float o = sigm(preact[2 * NHID + t]);
    float r = sigm(preact[3 * NHID + t]);
    float cn = tanhf(preact[4 * NHID + t]);
    float mt = tanhf(macc[t]);
    float ct = f * c_in[t] + i * cn + r * mt;
    float ht = o * tanhf(ct);
    out[4 + t] = ht;
    out[4 + NHID + t] = ct;
    ht_ws[t] = ht;
}

// hh = relu(W_ih·h_t + b_ih)
__global__ void k5_hh(const float* __restrict__ ht, const float* __restrict__ Wih,
                      const float* __restrict__ bih, float* __restrict__ hh) {
    int wave = threadIdx.x >> 6, lane = threadIdx.x & 63;
    int row = blockIdx.x * 4 + wave;
    const float4* w4 = (const float4*)(Wih + (size_t)row * NHID);
    const float4* h4 = (const float4*)ht;
    float p = 0.f;
#pragma unroll
    for (int j = 0; j < 4; ++j) {
        float4 wv = w4[j * 64 + lane];
        float4 hv = h4[j * 64 + lane];
        p += wv.x * hv.x + wv.y * hv.y + wv.z * hv.z + wv.w * hv.w;
    }
    p = wave_reduce_sum(p);
    if (lane == 0) hh[row] = fmaxf(p + bih[row], 0.f);
}

#define TF_ROUND(r) { x0 += x1; x1 = (x1 << r) | (x1 >> (32 - r)); x1 ^= x0; }

// actor/critic heads + jax.random.categorical(key(1), log pi) replication
__global__ void k6_heads(const float* __restrict__ hh, const float* __restrict__ Wa,
                         const float* __restrict__ ba, const float* __restrict__ Wc,
                         const float* __restrict__ bc, float* __restrict__ out) {
    __shared__ float zz[3];
    int wave = threadIdx.x >> 6, lane = threadIdx.x & 63;
    if (wave < 3) {
        const float* W = (wave == 2) ? Wc : Wa + wave * NHID;
        const float4* w4 = (const float4*)W;
        const float4* h4 = (const float4*)hh;
        float p = 0.f;
#pragma unroll
        for (int j = 0; j < 4; ++j) {
            float4 wv = w4[j * 64 + lane];
            float4 hv = h4[j * 64 + lane];
            p += wv.x * hv.x + wv.y * hv.y + wv.z * hv.z + wv.w * hv.w;
        }
        p = wave_reduce_sum(p);
        if (lane == 0) zz[wave] = p;
    }
    __syncthreads();
    if (threadIdx.x == 0) {
        float z0 = zz[0] + ba[0], z1 = zz[1] + ba[1], v = zz[2] + bc[0];
        float mz = fmaxf(z0, z1);
        float e0 = expf(z0 - mz), e1 = expf(z1 - mz);
        float sum = e0 + e1;
        float pi0 = e0 / sum, pi1 = e1 / sum;
        float lse = mz + logf(sum);
        // Threefry-2x32, key = (0,1) [jax.random.key(1)], counter = (0,1)
        unsigned ks0 = 0u, ks1 = 1u, ks2 = 0u ^ 1u ^ 0x1BD11BDAu;
        unsigned x0 = 0u + ks0, x1 = 1u + ks1;
        TF_ROUND(13) TF_ROUND(15) TF_ROUND(26) TF_ROUND(6)
        x0 += ks1; x1 += ks2 + 1u;
        TF_ROUND(17) TF_ROUND(29) TF_ROUND(16) TF_ROUND(24)
        x0 += ks2; x1 += ks0 + 2u;
        TF_ROUND(13) TF_ROUND(15) TF_ROUND(26) TF_ROUND(6)
        x0 += ks0; x1 += ks1 + 3u;
        TF_ROUND(17) TF_ROUND(29) TF_ROUND(16) TF_ROUND(24)
        x0 += ks1; x1 += ks2 + 4u;
        TF_ROUND(13) TF_ROUND(15) TF_ROUND(26) TF_ROUND(6)
        x0 += ks2; x1 += ks0 + 5u;
        // bits -> uniform [0,1) -> gumbel (matches jax: bitcast((bits>>9)|1.0f)-1)
        float u0 = __uint_as_float((x0 >> 9) | 0x3F800000u) - 1.0f;
        float u1 = __uint_as_float((x1 >> 9) | 0x3F800000u) - 1.0f;
        const float tiny = 1.17549435e-38f;
        u0 = fmaxf(u0, tiny); u1 = fmaxf(u1, tiny);
        float g0 = -logf(-logf(u0));
        float g1 = -logf(-logf(u1));
        int a = (z1 + g1 > z0 + g0) ? 1 : 0;  // argmax, first index wins ties
        float logp = (a ? z1 : z0) - lse;
        out[0] = pi0; out[1] = pi1; out[2] = v; out[3] = logp;
    }
}

extern "C" void kernel_launch(void* const* d_in, const int* in_sizes, int n_in,
                              void* d_out, int out_size, void* d_ws, size_t ws_size,
                              hipStream_t stream) {
    const float* x      = (const float*)d_in[0];
    const float* h      = (const float*)d_in[1];
    const float* c      = (const float*)d_in[2];
    const float* keys   = (const float*)d_in[3];
    const float* vals   = (const float*)d_in[4];
    const float* Wi2h   = (const float*)d_in[5];
    const float* bi2h   = (const float*)d_in[6];
    const float* Wh2h   = (const float*)d_in[7];
    const float* bh2h   = (const float*)d_in[8];
    const float* Wih    = (const float*)d_in[9];
    const float* bih    = (const float*)d_in[10];
    const float* Wact   = (const float*)d_in[11];
    const float* bact   = (const float*)d_in[12];
    const float* Wcrit  = (const float*)d_in[13];
    const float* bcrit  = (const float*)d_in[14];
    const int*   pick   = (const int*)d_in[15];
    float* out = (float*)d_out;
    float* ws  = (float*)d_ws;

    k_pre<<<5120 / 4, 256, 0, stream>>>(x, h, Wi2h, bi2h, Wh2h, bh2h, ws + WS_PREACT);
    k1_stats<<<NB1, 256, 0, stream>>>(keys, x, pick, ws + WS_BLOCKML);
    k2_combine<<<1, 512, 0, stream>>>(ws + WS_BLOCKML, ws + WS_ML, ws + WS_MACC);
    k3_pv<<<NB3, 256, 0, stream>>>(keys, x, pick, ws + WS_ML, vals, ws + WS_MACC);
    k4_cell<<<4, 256, 0, stream>>>(ws + WS_PREACT, ws + WS_MACC, c, out, ws + WS_HT);
    k5_hh<<<NHID / 4, 256, 0, stream>>>(ws + WS_HT, Wih, bih, ws + WS_HH);
    k6_heads<<<1, 256, 0, stream>>>(ws + WS_HH, Wact, bact, Wcrit, bcrit, out);
}

// Round 3
// 110.648 us; speedup vs baseline: 1.5727x; 1.5727x over previous
//
#include <hip/hip_runtime.h>
#include <math.h>

#define NHID 1024
#define NIN 14
#define NKEYS 100000
#define NRD 10
#define R3 50            // rows per PV block; 2000 * 50 = 100000 exactly
#define NB3 2000
#define NBPRE 1280       // 5120 preact rows / 4 per block
#define NSLOT 8

typedef float f32x4 __attribute__((ext_vector_type(4)));

// ws float-index layout
#define WS_MACC8   0         // NSLOT*1024 = 8192 floats
#define WS_L8      8192      // NSLOT floats
#define WS_PREACT  8208      // 5120 floats (16B aligned)
#define WS_HH      13328     // 1024
#define WS_HT      14352     // 1024
#define ZERO_BYTES ((8192 + NSLOT) * 4)

__device__ inline float wave_reduce_sum(float v) {
#pragma unroll
    for (int off = 32; off > 0; off >>= 1) v += __shfl_down(v, off, 64);
    return v;
}

__device__ inline float sigm(float x) { return 1.0f / (1.0f + expf(-x)); }

// load q (clamped dynamic_slice like JAX) and its norm
__device__ inline float load_q(const float* __restrict__ x, int pick, float* q) {
    int start = pick * NRD;
    if (start > NIN - NRD) start = NIN - NRD;
    if (start < 0) start = 0;
    float qn = 0.f;
#pragma unroll
    for (int k = 0; k < NRD; ++k) { q[k] = x[start + k]; qn = fmaf(q[k], q[k], qn); }
    return sqrtf(qn);
}

__device__ inline float score_for(const float* __restrict__ keys, int i,
                                  const float* q, float qn) {
    float dot = 0.f, kn = 0.f;
#pragma unroll
    for (int k = 0; k < NRD; ++k) {
        float kv = keys[(size_t)i * NRD + k];
        dot = fmaf(kv, q[k], dot);
        kn = fmaf(kv, kv, kn);
    }
    return dot / fmaxf(sqrtf(kn) * qn, 1e-8f);
}

// Fused: blocks [0, NB3) do the PV partial reduction (unnormalized, cos-sim
// scores are in [-1,1] so exp(s) is stable); blocks [NB3, NB3+NBPRE) compute
// preact rows.
__global__ void __launch_bounds__(256) kA(const float* __restrict__ keys,
                                          const float* __restrict__ x,
                                          const int* __restrict__ pick_arm,
                                          const float* __restrict__ vals,
                                          float* __restrict__ macc8,
                                          float* __restrict__ L8,
                                          const float* __restrict__ h,
                                          const float* __restrict__ Wi,
                                          const float* __restrict__ bi,
                                          const float* __restrict__ Wh,
                                          const float* __restrict__ bh,
                                          float* __restrict__ preact) {
    int tid = threadIdx.x;
    if (blockIdx.x < NB3) {
        __shared__ float wl[R3];
        int r0 = blockIdx.x * R3;
        int slot = blockIdx.x & (NSLOT - 1);
        float wv = 0.f;
        if (tid < R3) {
            float q[NRD];
            float qn = load_q(x, pick_arm[0], q);
            float sv = score_for(keys, r0 + tid, q, qn);
            wv = expf(sv);               // |sv| <= 1, no max needed
            wl[tid] = wv;
        }
        if (tid < 64) {                  // R3=50 lives entirely in wave 0
            float ls = wave_reduce_sum(wv);
            if (tid == 0) atomicAdd(&L8[slot], ls);
        }
        __syncthreads();
        const f32x4* vp = (const f32x4*)vals + ((size_t)r0 << 8) + tid;
        float ax = 0.f, ay = 0.f, az = 0.f, aw = 0.f;
#pragma unroll 5
        for (int r = 0; r < R3; ++r) {
            float w = wl[r];
            f32x4 v = __builtin_nontemporal_load(&vp[(size_t)r << 8]);
            ax = fmaf(w, v.x, ax);
            ay = fmaf(w, v.y, ay);
            az = fmaf(w, v.z, az);
            aw = fmaf(w, v.w, aw);
        }
        float* ms = macc8 + (size_t)slot * NHID;
        atomicAdd(&ms[4 * tid + 0], ax);
        atomicAdd(&ms[4 * tid + 1], ay);
        atomicAdd(&ms[4 * tid + 2], az);
        atomicAdd(&ms[4 * tid + 3], aw);
    } else {
        int wave = tid >> 6, lane = tid & 63;
        int row = (blockIdx.x - NB3) * 4 + wave;
        const float4* w4 = (const float4*)(Wh + (size_t)row * NHID);
        const float4* h4 = (const float4*)h;
        float p = 0.f;
#pragma unroll
        for (int j = 0; j < 4; ++j) {
            float4 wv = w4[j * 64 + lane];
            float4 hv = h4[j * 64 + lane];
            p += wv.x * hv.x + wv.y * hv.y + wv.z * hv.z + wv.w * hv.w;
        }
        if (lane < NIN) p += x[lane] * Wi[(size_t)row * NIN + lane];
        p = wave_reduce_sum(p);
        if (lane == 0) preact[row] = p + bi[row] + bh[row];
    }
}

// gates + cell update; write h_t, c_t to out and h_t to ws
__global__ void k4_cell(const float* __restrict__ preact, const float* __restrict__ macc8,
                        const float* __restrict__ L8, const float* __restrict__ c_in,
                        float* __restrict__ out, float* __restrict__ ht_ws) {
    int t = blockIdx.x * 256 + threadIdx.x;
    float Ls = 0.f, msum = 0.f;
#pragma unroll
    for (int s = 0; s < NSLOT; ++s) {
        Ls += L8[s];
        msum += macc8[(size_t)s * NHID + t];
    }
    float f = sigm(preact[t]);
    float i = sigm(preact[NHID + t]);
    float o = sigm(preact[2 * NHID + t]);
    float r = sigm(preact[3 * NHID + t]);
    float cn = tanhf(preact[4 * NHID + t]);
    float mt = tanhf(msum / Ls);
    float ct = f * c_in[t] + i * cn + r * mt;
    float ht = o * tanhf(ct);
    out[4 + t] = ht;
    out[4 + NHID + t] = ct;
    ht_ws[t] = ht;
}

// hh = relu(W_ih·h_t + b_ih)
__global__ void k5_hh(const float* __restrict__ ht, const float* __restrict__ Wih,
                      const float* __restrict__ bih, float* __restrict__ hh) {
    int wave = threadIdx.x >> 6, lane = threadIdx.x & 63;
    int row = blockIdx.x * 4 + wave;
    const float4* w4 = (const float4*)(Wih + (size_t)row * NHID);
    const float4* h4 = (const float4*)ht;
    float p = 0.f;
#pragma unroll
    for (int j = 0; j < 4; ++j) {
        float4 wv = w4[j * 64 + lane];
        float4 hv = h4[j * 64 + lane];
        p += wv.x * hv.x + wv.y * hv.y + wv.z * hv.z + wv.w * hv.w;
    }
    p = wave_reduce_sum(p);
    if (lane == 0) hh[row] = fmaxf(p + bih[row], 0.f);
}

#define TF_ROUND(r) { x0 += x1; x1 = (x1 << r) | (x1 >> (32 - r)); x1 ^= x0; }

// actor/critic heads + jax.random.categorical(key(1), log pi) replication
__global__ void k6_heads(const float* __restrict__ hh, const float* __restrict__ Wa,
                         const float* __restrict__ ba, const float* __restrict__ Wc,
                         const float* __restrict__ bc, float* __restrict__ out) {
    __shared__ float zz[3];
    int wave = threadIdx.x >> 6, lane = threadIdx.x & 63;
    if (wave < 3) {
        const float* W = (wave == 2) ? Wc : Wa + wave * NHID;
        const float4* w4 = (const float4*)W;
        const float4* h4 = (const float4*)hh;
        float p = 0.f;
#pragma unroll
        for (int j = 0; j < 4; ++j) {
            float4 wv = w4[j * 64 + lane];
            float4 hv = h4[j * 64 + lane];
            p += wv.x * hv.x + wv.y * hv.y + wv.z * hv.z + wv.w * hv.w;
        }
        p = wave_reduce_sum(p);
        if (lane == 0) zz[wave] = p;
    }
    __syncthreads();
    if (threadIdx.x == 0) {
        float z0 = zz[0] + ba[0], z1 = zz[1] + ba[1], v = zz[2] + bc[0];
        float mz = fmaxf(z0, z1);
        float e0 = expf(z0 - mz), e1 = expf(z1 - mz);
        float sum = e0 + e1;
        float pi0 = e0 / sum, pi1 = e1 / sum;
        float lse = mz + logf(sum);
        // Threefry-2x32, key = (0,1) [jax.random.key(1)], counter = (0,1)
        unsigned ks0 = 0u, ks1 = 1u, ks2 = 0u ^ 1u ^ 0x1BD11BDAu;
        unsigned x0 = 0u + ks0, x1 = 1u + ks1;
        TF_ROUND(13) TF_ROUND(15) TF_ROUND(26) TF_ROUND(6)
        x0 += ks1; x1 += ks2 + 1u;
        TF_ROUND(17) TF_ROUND(29) TF_ROUND(16) TF_ROUND(24)
        x0 += ks2; x1 += ks0 + 2u;
        TF_ROUND(13) TF_ROUND(15) TF_ROUND(26) TF_ROUND(6)
        x0 += ks0; x1 += ks1 + 3u;
        TF_ROUND(17) TF_ROUND(29) TF_ROUND(16) TF_ROUND(24)
        x0 += ks1; x1 += ks2 + 4u;
        TF_ROUND(13) TF_ROUND(15) TF_ROUND(26) TF_ROUND(6)
        x0 += ks2; x1 += ks0 + 5u;
        float u0 = __uint_as_float((x0 >> 9) | 0x3F800000u) - 1.0f;
        float u1 = __uint_as_float((x1 >> 9) | 0x3F800000u) - 1.0f;
        const float tiny = 1.17549435e-38f;
        u0 = fmaxf(u0, tiny); u1 = fmaxf(u1, tiny);
        float g0 = -logf(-logf(u0));
        float g1 = -logf(-logf(u1));
        int a = (z1 + g1 > z0 + g0) ? 1 : 0;
        float logp = (a ? z1 : z0) - lse;
        out[0] = pi0; out[1] = pi1; out[2] = v; out[3] = logp;
    }
}

extern "C" void kernel_launch(void* const* d_in, const int* in_sizes, int n_in,
                              void* d_out, int out_size, void* d_ws, size_t ws_size,
                              hipStream_t stream) {
    const float* x      = (const float*)d_in[0];
    const float* h      = (const float*)d_in[1];
    const float* c      = (const float*)d_in[2];
    const float* keys   = (const float*)d_in[3];
    const float* vals   = (const float*)d_in[4];
    const float* Wi2h   = (const float*)d_in[5];
    const float* bi2h   = (const float*)d_in[6];
    const float* Wh2h   = (const float*)d_in[7];
    const float* bh2h   = (const float*)d_in[8];
    const float* Wih    = (const float*)d_in[9];
    const float* bih    = (const float*)d_in[10];
    const float* Wact   = (const float*)d_in[11];
    const float* bact   = (const float*)d_in[12];
    const float* Wcrit  = (const float*)d_in[13];
    const float* bcrit  = (const float*)d_in[14];
    const int*   pick   = (const int*)d_in[15];
    float* out = (float*)d_out;
    float* ws  = (float*)d_ws;

    (void)hipMemsetAsync(ws, 0, ZERO_BYTES, stream);
    kA<<<NB3 + NBPRE, 256, 0, stream>>>(keys, x, pick, vals,
                                        ws + WS_MACC8, ws + WS_L8,
                                        h, Wi2h, bi2h, Wh2h, bh2h, ws + WS_PREACT);
    k4_cell<<<4, 256, 0, stream>>>(ws + WS_PREACT, ws + WS_MACC8, ws + WS_L8,
                                   c, out, ws + WS_HT);
    k5_hh<<<NHID / 4, 256, 0, stream>>>(ws + WS_HT, Wih, bih, ws + WS_HH);
    k6_heads<<<1, 256, 0, stream>>>(ws + WS_HH, Wact, bact, Wcrit, bcrit, out);
}

// Round 4
// 107.871 us; speedup vs baseline: 1.6132x; 1.0257x over previous
//
#include <hip/hip_runtime.h>
#include <math.h>

#define NHID 1024
#define NIN 14
#define NKEYS 100000
#define NRD 10
#define R3 50            // rows per PV block; 2000 * 50 = 100000 exactly
#define NB3 2000
#define NBPRE 1280       // 5120 preact rows / 4 per block
#define NSLOT 16

typedef float f32x4 __attribute__((ext_vector_type(4)));

// ws float-index layout
#define WS_MACC    0         // NSLOT*1024 = 16384 floats
#define WS_L       16384     // NSLOT floats
#define WS_PREACT  16400     // 5120 floats (16B aligned: 16400*4=65600=16*4100)
#define WS_HH      21520     // 1024
#define ZERO_BYTES ((16384 + NSLOT) * 4)

__device__ inline float wave_reduce_sum(float v) {
#pragma unroll
    for (int off = 32; off > 0; off >>= 1) v += __shfl_down(v, off, 64);
    return v;
}

__device__ inline float sigm(float x) { return 1.0f / (1.0f + expf(-x)); }

// load q (clamped dynamic_slice like JAX) and its norm
__device__ inline float load_q(const float* __restrict__ x, int pick, float* q) {
    int start = pick * NRD;
    if (start > NIN - NRD) start = NIN - NRD;
    if (start < 0) start = 0;
    float qn = 0.f;
#pragma unroll
    for (int k = 0; k < NRD; ++k) { q[k] = x[start + k]; qn = fmaf(q[k], q[k], qn); }
    return sqrtf(qn);
}

__device__ inline float score_for(const float* __restrict__ keys, int i,
                                  const float* q, float qn) {
    float dot = 0.f, kn = 0.f;
#pragma unroll
    for (int k = 0; k < NRD; ++k) {
        float kv = keys[(size_t)i * NRD + k];
        dot = fmaf(kv, q[k], dot);
        kn = fmaf(kv, kv, kn);
    }
    return dot / fmaxf(sqrtf(kn) * qn, 1e-8f);
}

// Fused: blocks [0, NB3) do the PV partial reduction (unnormalized; cos-sim
// scores are in [-1,1] so exp(s) is stable); blocks [NB3, NB3+NBPRE) compute
// preact rows.
__global__ void __launch_bounds__(256) kA(const float* __restrict__ keys,
                                          const float* __restrict__ x,
                                          const int* __restrict__ pick_arm,
                                          const float* __restrict__ vals,
                                          float* __restrict__ macc,
                                          float* __restrict__ Lacc,
                                          const float* __restrict__ h,
                                          const float* __restrict__ Wi,
                                          const float* __restrict__ bi,
                                          const float* __restrict__ Wh,
                                          const float* __restrict__ bh,
                                          float* __restrict__ preact) {
    int tid = threadIdx.x;
    if (blockIdx.x < NB3) {
        __shared__ float wl[R3];
        int r0 = blockIdx.x * R3;
        int slot = blockIdx.x & (NSLOT - 1);
        float wv = 0.f;
        if (tid < R3) {
            float q[NRD];
            float qn = load_q(x, pick_arm[0], q);
            float sv = score_for(keys, r0 + tid, q, qn);
            wv = expf(sv);               // |sv| <= 1, no max needed
            wl[tid] = wv;
        }
        if (tid < 64) {                  // R3=50 lives entirely in wave 0
            float ls = wave_reduce_sum(wv);
            if (tid == 0) atomicAdd(&Lacc[slot], ls);
        }
        __syncthreads();
        const f32x4* vp = (const f32x4*)vals + ((size_t)r0 << 8) + tid;
        float ax = 0.f, ay = 0.f, az = 0.f, aw = 0.f;
#pragma unroll 10
        for (int r = 0; r < R3; ++r) {
            float w = wl[r];
            f32x4 v = __builtin_nontemporal_load(&vp[(size_t)r << 8]);
            ax = fmaf(w, v.x, ax);
            ay = fmaf(w, v.y, ay);
            az = fmaf(w, v.z, az);
            aw = fmaf(w, v.w, aw);
        }
        float* ms = macc + (size_t)slot * NHID;
        atomicAdd(&ms[4 * tid + 0], ax);
        atomicAdd(&ms[4 * tid + 1], ay);
        atomicAdd(&ms[4 * tid + 2], az);
        atomicAdd(&ms[4 * tid + 3], aw);
    } else {
        int wave = tid >> 6, lane = tid & 63;
        int row = (blockIdx.x - NB3) * 4 + wave;
        const f32x4* w4 = (const f32x4*)(Wh + (size_t)row * NHID);
        const f32x4* h4 = (const f32x4*)h;
        float p = 0.f;
#pragma unroll
        for (int j = 0; j < 4; ++j) {
            f32x4 wv = __builtin_nontemporal_load(&w4[j * 64 + lane]);
            f32x4 hv = h4[j * 64 + lane];
            p += wv.x * hv.x + wv.y * hv.y + wv.z * hv.z + wv.w * hv.w;
        }
        if (lane < NIN) p += x[lane] * Wi[(size_t)row * NIN + lane];
        p = wave_reduce_sum(p);
        if (lane == 0) preact[row] = p + bi[row] + bh[row];
    }
}

// Fused cell update + hidden GEMV. Every block redundantly computes the full
// 1024-wide cell update (L2-hot inputs), stashes h_t in LDS, then computes its
// 4 rows of hh = relu(W_ih . h_t + b_ih). Block 0 also writes h_t/c_t to out.
__global__ void __launch_bounds__(256) k45(const float* __restrict__ preact,
                                           const float* __restrict__ macc,
                                           const float* __restrict__ Lacc,
                                           const float* __restrict__ c_in,
                                           const float* __restrict__ Wih,
                                           const float* __restrict__ bih,
                                           float* __restrict__ out,
                                           float* __restrict__ hh) {
    __shared__ float hlds[NHID];
    int tid = threadIdx.x;
    float Ls = 0.f;
#pragma unroll
    for (int s = 0; s < NSLOT; ++s) Ls += Lacc[s];
    float invL = 1.0f / Ls;
    const f32x4* pre4 = (const f32x4*)preact;
    f32x4 fg = pre4[tid];
    f32x4 ig = pre4[256 + tid];
    f32x4 og = pre4[512 + tid];
    f32x4 rg = pre4[768 + tid];
    f32x4 gg = pre4[1024 + tid];
    f32x4 m4 = {0.f, 0.f, 0.f, 0.f};
#pragma unroll
    for (int s = 0; s < NSLOT; ++s) m4 += ((const f32x4*)(macc + (size_t)s * NHID))[tid];
    f32x4 c4 = ((const f32x4*)c_in)[tid];
    f32x4 h4, ct4;
#pragma unroll
    for (int e = 0; e < 4; ++e) {
        float f = sigm(fg[e]);
        float i = sigm(ig[e]);
        float o = sigm(og[e]);
        float r = sigm(rg[e]);
        float cn = tanhf(gg[e]);
        float mt = tanhf(m4[e] * invL);
        float ct = f * c4[e] + i * cn + r * mt;
        ct4[e] = ct;
        h4[e] = o * tanhf(ct);
    }
    ((f32x4*)hlds)[tid] = h4;
    if (blockIdx.x == 0) {
        ((f32x4*)(out + 4))[tid] = h4;
        ((f32x4*)(out + 4 + NHID))[tid] = ct4;
    }
    __syncthreads();
    int wave = tid >> 6, lane = tid & 63;
    int row = blockIdx.x * 4 + wave;
    const f32x4* w4 = (const f32x4*)(Wih + (size_t)row * NHID);
    const f32x4* hl4 = (const f32x4*)hlds;
    float p = 0.f;
#pragma unroll
    for (int j = 0; j < 4; ++j) {
        f32x4 wv = __builtin_nontemporal_load(&w4[j * 64 + lane]);
        f32x4 hv = hl4[j * 64 + lane];
        p += wv.x * hv.x + wv.y * hv.y + wv.z * hv.z + wv.w * hv.w;
    }
    p = wave_reduce_sum(p);
    if (lane == 0) hh[row] = fmaxf(p + bih[row], 0.f);
}

#define TF_ROUND(r) { x0 += x1; x1 = (x1 << r) | (x1 >> (32 - r)); x1 ^= x0; }

// actor/critic heads + jax.random.categorical(key(1), log pi) replication
__global__ void k6_heads(const float* __restrict__ hh, const float* __restrict__ Wa,
                         const float* __restrict__ ba, const float* __restrict__ Wc,
                         const float* __restrict__ bc, float* __restrict__ out) {
    __shared__ float zz[3];
    int wave = threadIdx.x >> 6, lane = threadIdx.x & 63;
    if (wave < 3) {
        const float* W = (wave == 2) ? Wc : Wa + wave * NHID;
        const f32x4* w4 = (const f32x4*)W;
        const f32x4* h4 = (const f32x4*)hh;
        float p = 0.f;
#pragma unroll
        for (int j = 0; j < 4; ++j) {
            f32x4 wv = w4[j * 64 + lane];
            f32x4 hv = h4[j * 64 + lane];
            p += wv.x * hv.x + wv.y * hv.y + wv.z * hv.z + wv.w * hv.w;
        }
        p = wave_reduce_sum(p);
        if (lane == 0) zz[wave] = p;
    }
    __syncthreads();
    if (threadIdx.x == 0) {
        float z0 = zz[0] + ba[0], z1 = zz[1] + ba[1], v = zz[2] + bc[0];
        float mz = fmaxf(z0, z1);
        float e0 = expf(z0 - mz), e1 = expf(z1 - mz);
        float sum = e0 + e1;
        float pi0 = e0 / sum, pi1 = e1 / sum;
        float lse = mz + logf(sum);
        // Threefry-2x32, key = (0,1) [jax.random.key(1)], counter = (0,1)
        unsigned ks0 = 0u, ks1 = 1u, ks2 = 0u ^ 1u ^ 0x1BD11BDAu;
        unsigned x0 = 0u + ks0, x1 = 1u + ks1;
        TF_ROUND(13) TF_ROUND(15) TF_ROUND(26) TF_ROUND(6)
        x0 += ks1; x1 += ks2 + 1u;
        TF_ROUND(17) TF_ROUND(29) TF_ROUND(16) TF_ROUND(24)
        x0 += ks2; x1 += ks0 + 2u;
        TF_ROUND(13) TF_ROUND(15) TF_ROUND(26) TF_ROUND(6)
        x0 += ks0; x1 += ks1 + 3u;
        TF_ROUND(17) TF_ROUND(29) TF_ROUND(16) TF_ROUND(24)
        x0 += ks1; x1 += ks2 + 4u;
        TF_ROUND(13) TF_ROUND(15) TF_ROUND(26) TF_ROUND(6)
        x0 += ks2; x1 += ks0 + 5u;
        float u0 = __uint_as_float((x0 >> 9) | 0x3F800000u) - 1.0f;
        float u1 = __uint_as_float((x1 >> 9) | 0x3F800000u) - 1.0f;
        const float tiny = 1.17549435e-38f;
        u0 = fmaxf(u0, tiny); u1 = fmaxf(u1, tiny);
        float g0 = -logf(-logf(u0));
        float g1 = -logf(-logf(u1));
        int a = (z1 + g1 > z0 + g0) ? 1 : 0;
        float logp = (a ? z1 : z0) - lse;
        out[0] = pi0; out[1] = pi1; out[2] = v; out[3] = logp;
    }
}

extern "C" void kernel_launch(void* const* d_in, const int* in_sizes, int n_in,
                              void* d_out, int out_size, void* d_ws, size_t ws_size,
                              hipStream_t stream) {
    const float* x      = (const float*)d_in[0];
    const float* h      = (const float*)d_in[1];
    const float* c      = (const float*)d_in[2];
    const float* keys   = (const float*)d_in[3];
    const float* vals   = (const float*)d_in[4];
    const float* Wi2h   = (const float*)d_in[5];
    const float* bi2h   = (const float*)d_in[6];
    const float* Wh2h   = (const float*)d_in[7];
    const float* bh2h   = (const float*)d_in[8];
    const float* Wih    = (const float*)d_in[9];
    const float* bih    = (const float*)d_in[10];
    const float* Wact   = (const float*)d_in[11];
    const float* bact   = (const float*)d_in[12];
    const float* Wcrit  = (const float*)d_in[13];
    const float* bcrit  = (const float*)d_in[14];
    const int*   pick   = (const int*)d_in[15];
    float* out = (float*)d_out;
    float* ws  = (float*)d_ws;

    (void)hipMemsetAsync(ws, 0, ZERO_BYTES, stream);
    kA<<<NB3 + NBPRE, 256, 0, stream>>>(keys, x, pick, vals,
                                        ws + WS_MACC, ws + WS_L,
                                        h, Wi2h, bi2h, Wh2h, bh2h, ws + WS_PREACT);
    k45<<<NHID / 4, 256, 0, stream>>>(ws + WS_PREACT, ws + WS_MACC, ws + WS_L,
                                      c, Wih, bih, out, ws + WS_HH);
    k6_heads<<<1, 256, 0, stream>>>(ws + WS_HH, Wact, bact, Wcrit, bcrit, out);
}

// Round 5
// 95.153 us; speedup vs baseline: 1.8288x; 1.1337x over previous
//
#include <hip/hip_runtime.h>
#include <math.h>

#define NHID 1024
#define NIN 14
#define NKEYS 100000
#define NRD 10
#define R3 100           // rows per PV block; 1000 * 100 = 100000 exactly
#define NB3 1000
#define NBPRE 1280       // 5120 preact rows / 4 per block
#define NSLOT 16

typedef float f32x4 __attribute__((ext_vector_type(4)));

// ws float-index layout
#define WS_MACC    0         // NSLOT*1024 = 16384 floats
#define WS_L       16384     // NSLOT floats
#define WS_PREACT  16400     // 5120 floats (16B aligned: 16400*4=65600)
#define WS_HH      21520     // 1024
#define ZERO_BYTES ((16384 + NSLOT) * 4)

__device__ inline float wave_reduce_sum(float v) {
#pragma unroll
    for (int off = 32; off > 0; off >>= 1) v += __shfl_down(v, off, 64);
    return v;
}

__device__ inline float sigm(float x) { return 1.0f / (1.0f + expf(-x)); }

// load q (clamped dynamic_slice like JAX) and its norm
__device__ inline float load_q(const float* __restrict__ x, int pick, float* q) {
    int start = pick * NRD;
    if (start > NIN - NRD) start = NIN - NRD;
    if (start < 0) start = 0;
    float qn = 0.f;
#pragma unroll
    for (int k = 0; k < NRD; ++k) { q[k] = x[start + k]; qn = fmaf(q[k], q[k], qn); }
    return sqrtf(qn);
}

__device__ inline float score_for(const float* __restrict__ keys, int i,
                                  const float* q, float qn) {
    float dot = 0.f, kn = 0.f;
#pragma unroll
    for (int k = 0; k < NRD; ++k) {
        float kv = keys[(size_t)i * NRD + k];
        dot = fmaf(kv, q[k], dot);
        kn = fmaf(kv, kv, kn);
    }
    return dot / fmaxf(sqrtf(kn) * qn, 1e-8f);
}

// Fused: blocks [0, NB3) do the PV partial reduction (unnormalized; cos-sim
// scores are in [-1,1] so exp(s) is stable, no max pass); blocks
// [NB3, NB3+NBPRE) compute preact rows. No LDS / no __syncthreads in the PV
// path: every wave redundantly computes its block's 100 scores (keys rows are
// L2/L3-hot) and the stream loop broadcasts weights via __shfl.
__global__ void __launch_bounds__(256) kA(const float* __restrict__ keys,
                                          const float* __restrict__ x,
                                          const int* __restrict__ pick_arm,
                                          const float* __restrict__ vals,
                                          float* __restrict__ macc,
                                          float* __restrict__ Lacc,
                                          const float* __restrict__ h,
                                          const float* __restrict__ Wi,
                                          const float* __restrict__ bi,
                                          const float* __restrict__ Wh,
                                          const float* __restrict__ bh,
                                          float* __restrict__ preact) {
    int tid = threadIdx.x;
    if (blockIdx.x < NB3) {
        int r0 = blockIdx.x * R3;
        int slot = blockIdx.x & (NSLOT - 1);
        int lane = tid & 63;
        float wva = 0.f, wvb = 0.f;
        if (lane < 50) {
            float q[NRD];
            float qn = load_q(x, pick_arm[0], q);
            wva = expf(score_for(keys, r0 + lane, q, qn));
            wvb = expf(score_for(keys, r0 + 50 + lane, q, qn));
        }
        if (tid < 64) {                  // wave 0 contributes the L partial
            float ls = wave_reduce_sum(wva + wvb);
            if (tid == 0) atomicAdd(&Lacc[slot], ls);
        }
        const f32x4* vp = (const f32x4*)vals + ((size_t)r0 << 8) + tid;
        float ax = 0.f, ay = 0.f, az = 0.f, aw = 0.f;
#pragma unroll 10
        for (int r = 0; r < 50; ++r) {
            float w = __shfl(wva, r, 64);
            f32x4 v = __builtin_nontemporal_load(&vp[(size_t)r << 8]);
            ax = fmaf(w, v.x, ax);
            ay = fmaf(w, v.y, ay);
            az = fmaf(w, v.z, az);
            aw = fmaf(w, v.w, aw);
        }
        vp += (size_t)50 << 8;
#pragma unroll 10
        for (int r = 0; r < 50; ++r) {
            float w = __shfl(wvb, r, 64);
            f32x4 v = __builtin_nontemporal_load(&vp[(size_t)r << 8]);
            ax = fmaf(w, v.x, ax);
            ay = fmaf(w, v.y, ay);
            az = fmaf(w, v.z, az);
            aw = fmaf(w, v.w, aw);
        }
        float* ms = macc + (size_t)slot * NHID;
        atomicAdd(&ms[4 * tid + 0], ax);
        atomicAdd(&ms[4 * tid + 1], ay);
        atomicAdd(&ms[4 * tid + 2], az);
        atomicAdd(&ms[4 * tid + 3], aw);
    } else {
        int wave = tid >> 6, lane = tid & 63;
        int row = (blockIdx.x - NB3) * 4 + wave;
        const f32x4* w4 = (const f32x4*)(Wh + (size_t)row * NHID);
        const f32x4* h4 = (const f32x4*)h;
        float p = 0.f;
#pragma unroll
        for (int j = 0; j < 4; ++j) {
            f32x4 wv = __builtin_nontemporal_load(&w4[j * 64 + lane]);
            f32x4 hv = h4[j * 64 + lane];
            p += wv.x * hv.x + wv.y * hv.y + wv.z * hv.z + wv.w * hv.w;
        }
        if (lane < NIN) p += x[lane] * Wi[(size_t)row * NIN + lane];
        p = wave_reduce_sum(p);
        if (lane == 0) preact[row] = p + bi[row] + bh[row];
    }
}

// Fused cell update + hidden GEMV. Every block redundantly computes the full
// 1024-wide cell update (L2-hot inputs), stashes h_t in LDS, then computes its
// 4 rows of hh = relu(W_ih . h_t + b_ih). Block 0 also writes h_t/c_t to out.
__global__ void __launch_bounds__(256) k45(const float* __restrict__ preact,
                                           const float* __restrict__ macc,
                                           const float* __restrict__ Lacc,
                                           const float* __restrict__ c_in,
                                           const float* __restrict__ Wih,
                                           const float* __restrict__ bih,
                                           float* __restrict__ out,
                                           float* __restrict__ hh) {
    __shared__ float hlds[NHID];
    int tid = threadIdx.x;
    float Ls = 0.f;
#pragma unroll
    for (int s = 0; s < NSLOT; ++s) Ls += Lacc[s];
    float invL = 1.0f / Ls;
    const f32x4* pre4 = (const f32x4*)preact;
    f32x4 fg = pre4[tid];
    f32x4 ig = pre4[256 + tid];
    f32x4 og = pre4[512 + tid];
    f32x4 rg = pre4[768 + tid];
    f32x4 gg = pre4[1024 + tid];
    f32x4 m4 = {0.f, 0.f, 0.f, 0.f};
#pragma unroll
    for (int s = 0; s < NSLOT; ++s) m4 += ((const f32x4*)(macc + (size_t)s * NHID))[tid];
    f32x4 c4 = ((const f32x4*)c_in)[tid];
    f32x4 h4, ct4;
#pragma unroll
    for (int e = 0; e < 4; ++e) {
        float f = sigm(fg[e]);
        float i = sigm(ig[e]);
        float o = sigm(og[e]);
        float r = sigm(rg[e]);
        float cn = tanhf(gg[e]);
        float mt = tanhf(m4[e] * invL);
        float ct = f * c4[e] + i * cn + r * mt;
        ct4[e] = ct;
        h4[e] = o * tanhf(ct);
    }
    ((f32x4*)hlds)[tid] = h4;
    if (blockIdx.x == 0) {
        ((f32x4*)(out + 4))[tid] = h4;
        ((f32x4*)(out + 4 + NHID))[tid] = ct4;
    }
    __syncthreads();
    int wave = tid >> 6, lane = tid & 63;
    int row = blockIdx.x * 4 + wave;
    const f32x4* w4 = (const f32x4*)(Wih + (size_t)row * NHID);
    const f32x4* hl4 = (const f32x4*)hlds;
    float p = 0.f;
#pragma unroll
    for (int j = 0; j < 4; ++j) {
        f32x4 wv = __builtin_nontemporal_load(&w4[j * 64 + lane]);
        f32x4 hv = hl4[j * 64 + lane];
        p += wv.x * hv.x + wv.y * hv.y + wv.z * hv.z + wv.w * hv.w;
    }
    p = wave_reduce_sum(p);
    if (lane == 0) hh[row] = fmaxf(p + bih[row], 0.f);
}

#define TF_ROUND(r) { x0 += x1; x1 = (x1 << r) | (x1 >> (32 - r)); x1 ^= x0; }

// actor/critic heads + jax.random.categorical(key(1), log pi) replication
__global__ void k6_heads(const float* __restrict__ hh, const float* __restrict__ Wa,
                         const float* __restrict__ ba, const float* __restrict__ Wc,
                         const float* __restrict__ bc, float* __restrict__ out) {
    __shared__ float zz[3];
    int wave = threadIdx.x >> 6, lane = threadIdx.x & 63;
    if (wave < 3) {
        const float* W = (wave == 2) ? Wc : Wa + wave * NHID;
        const f32x4* w4 = (const f32x4*)W;
        const f32x4* h4 = (const f32x4*)hh;
        float p = 0.f;
#pragma unroll
        for (int j = 0; j < 4; ++j) {
            f32x4 wv = w4[j * 64 + lane];
            f32x4 hv = h4[j * 64 + lane];
            p += wv.x * hv.x + wv.y * hv.y + wv.z * hv.z + wv.w * hv.w;
        }
        p = wave_reduce_sum(p);
        if (lane == 0) zz[wave] = p;
    }
    __syncthreads();
    if (threadIdx.x == 0) {
        float z0 = zz[0] + ba[0], z1 = zz[1] + ba[1], v = zz[2] + bc[0];
        float mz = fmaxf(z0, z1);
        float e0 = expf(z0 - mz), e1 = expf(z1 - mz);
        float sum = e0 + e1;
        float pi0 = e0 / sum, pi1 = e1 / sum;
        float lse = mz + logf(sum);
        // Threefry-2x32, key = (0,1) [jax.random.key(1)], counter = (0,1)
        unsigned ks0 = 0u, ks1 = 1u, ks2 = 0u ^ 1u ^ 0x1BD11BDAu;
        unsigned x0 = 0u + ks0, x1 = 1u + ks1;
        TF_ROUND(13) TF_ROUND(15) TF_ROUND(26) TF_ROUND(6)
        x0 += ks1; x1 += ks2 + 1u;
        TF_ROUND(17) TF_ROUND(29) TF_ROUND(16) TF_ROUND(24)
        x0 += ks2; x1 += ks0 + 2u;
        TF_ROUND(13) TF_ROUND(15) TF_ROUND(26) TF_ROUND(6)
        x0 += ks0; x1 += ks1 + 3u;
        TF_ROUND(17) TF_ROUND(29) TF_ROUND(16) TF_ROUND(24)
        x0 += ks1; x1 += ks2 + 4u;
        TF_ROUND(13) TF_ROUND(15) TF_ROUND(26) TF_ROUND(6)
        x0 += ks2; x1 += ks0 + 5u;
        float u0 = __uint_as_float((x0 >> 9) | 0x3F800000u) - 1.0f;
        float u1 = __uint_as_float((x1 >> 9) | 0x3F800000u) - 1.0f;
        const float tiny = 1.17549435e-38f;
        u0 = fmaxf(u0, tiny); u1 = fmaxf(u1, tiny);
        float g0 = -logf(-logf(u0));
        float g1 = -logf(-logf(u1));
        int a = (z1 + g1 > z0 + g0) ? 1 : 0;
        float logp = (a ? z1 : z0) - lse;
        out[0] = pi0; out[1] = pi1; out[2] = v; out[3] = logp;
    }
}

extern "C" void kernel_launch(void* const* d_in, const int* in_sizes, int n_in,
                              void* d_out, int out_size, void* d_ws, size_t ws_size,
                              hipStream_t stream) {
    const float* x      = (const float*)d_in[0];
    const float* h      = (const float*)d_in[1];
    const float* c      = (const float*)d_in[2];
    const float* keys   = (const float*)d_in[3];
    const float* vals   = (const float*)d_in[4];
    const float* Wi2h   = (const float*)d_in[5];
    const float* bi2h   = (const float*)d_in[6];
    const float* Wh2h   = (const float*)d_in[7];
    const float* bh2h   = (const float*)d_in[8];
    const float* Wih    = (const float*)d_in[9];
    const float* bih    = (const float*)d_in[10];
    const float* Wact   = (const float*)d_in[11];
    const float* bact   = (const float*)d_in[12];
    const float* Wcrit  = (const float*)d_in[13];
    const float* bcrit  = (const float*)d_in[14];
    const int*   pick   = (const int*)d_in[15];
    float* out = (float*)d_out;
    float* ws  = (float*)d_ws;

    (void)hipMemsetAsync(ws, 0, ZERO_BYTES, stream);
    kA<<<NB3 + NBPRE, 256, 0, stream>>>(keys, x, pick, vals,
                                        ws + WS_MACC, ws + WS_L,
                                        h, Wi2h, bi2h, Wh2h, bh2h, ws + WS_PREACT);
    k45<<<NHID / 4, 256, 0, stream>>>(ws + WS_PREACT, ws + WS_MACC, ws + WS_L,
                                      c, Wih, bih, out, ws + WS_HH);
    k6_heads<<<1, 256, 0, stream>>>(ws + WS_HH, Wact, bact, Wcrit, bcrit, out);
}

// Round 6
// 90.740 us; speedup vs baseline: 1.9178x; 1.0486x over previous
//
#include <hip/hip_runtime.h>
#include <math.h>

#define NHID 1024
#define NIN 14
#define NKEYS 100000
#define NRD 10
#define R3 100           // rows per PV block; 1000 * 100 = 100000 exactly
#define NB3 1000
#define NBPRE 1280       // 5120 preact rows / 4 per block
#define NSLOT 16
#define NPF 10           // vals prefetch depth (f32x4 regs/thread)

typedef float f32x4 __attribute__((ext_vector_type(4)));

// ws float-index layout
#define WS_MACC    0         // NSLOT*1024 = 16384 floats
#define WS_L       16384     // NSLOT floats
#define WS_PREACT  16400     // 5120 floats (16B aligned: 16400*4=65600)
#define WS_HH      21520     // 1024
#define ZERO_BYTES ((16384 + NSLOT) * 4)

__device__ inline float wave_reduce_sum(float v) {
#pragma unroll
    for (int off = 32; off > 0; off >>= 1) v += __shfl_down(v, off, 64);
    return v;
}

__device__ inline float sigm(float x) { return 1.0f / (1.0f + expf(-x)); }

__device__ inline float bcast_lane(float v, int lane) {
    return __uint_as_float(__builtin_amdgcn_readlane(__float_as_uint(v), lane));
}

// load q (clamped dynamic_slice like JAX) and its norm
__device__ inline float load_q(const float* __restrict__ x, int pick, float* q) {
    int start = pick * NRD;
    if (start > NIN - NRD) start = NIN - NRD;
    if (start < 0) start = 0;
    float qn = 0.f;
#pragma unroll
    for (int k = 0; k < NRD; ++k) { q[k] = x[start + k]; qn = fmaf(q[k], q[k], qn); }
    return sqrtf(qn);
}

__device__ inline float score_for(const float* __restrict__ keys, int i,
                                  const float* q, float qn) {
    float dot = 0.f, kn = 0.f;
#pragma unroll
    for (int k = 0; k < NRD; ++k) {
        float kv = keys[(size_t)i * NRD + k];
        dot = fmaf(kv, q[k], dot);
        kn = fmaf(kv, kv, kn);
    }
    return dot / fmaxf(sqrtf(kn) * qn, 1e-8f);
}

// Fused: blocks [0, NB3) do the PV partial reduction (unnormalized; cos-sim
// scores are in [-1,1] so exp(s) is stable, no max pass); blocks
// [NB3, NB3+NBPRE) compute preact rows. PV path: software-pipelined — NPF
// nontemporal vals loads are issued BEFORE the (redundant per-wave) score
// computation so streaming starts at block start; weight broadcast via
// v_readlane (compile-time lane), no LDS, no __syncthreads.
__global__ void __launch_bounds__(256) kA(const float* __restrict__ keys,
                                          const float* __restrict__ x,
                                          const int* __restrict__ pick_arm,
                                          const float* __restrict__ vals,
                                          float* __restrict__ macc,
                                          float* __restrict__ Lacc,
                                          const float* __restrict__ h,
                                          const float* __restrict__ Wi,
                                          const float* __restrict__ bi,
                                          const float* __restrict__ Wh,
                                          const float* __restrict__ bh,
                                          float* __restrict__ preact) {
    int tid = threadIdx.x;
    if (blockIdx.x < NB3) {
        int r0 = blockIdx.x * R3;
        int slot = blockIdx.x & (NSLOT - 1);
        int lane = tid & 63;
        const f32x4* vp = (const f32x4*)vals + ((size_t)r0 << 8) + tid;
        // issue the first NPF stream loads before any score work
        f32x4 buf[NPF];
#pragma unroll
        for (int j = 0; j < NPF; ++j)
            buf[j] = __builtin_nontemporal_load(&vp[(size_t)j << 8]);
        // redundant per-wave score computation (keys rows are L2-hot)
        float wva = 0.f, wvb = 0.f;
        if (lane < 50) {
            float q[NRD];
            float qn = load_q(x, pick_arm[0], q);
            wva = expf(score_for(keys, r0 + lane, q, qn));
            wvb = expf(score_for(keys, r0 + 50 + lane, q, qn));
        }
        if (tid < 64) {                  // wave 0 contributes the L partial
            float ls = wave_reduce_sum(wva + wvb);
            if (tid == 0) atomicAdd(&Lacc[slot], ls);
        }
        float ax = 0.f, ay = 0.f, az = 0.f, aw = 0.f;
#pragma unroll
        for (int r = 0; r < R3; ++r) {
            float w = (r < 50) ? bcast_lane(wva, r) : bcast_lane(wvb, r - 50);
            f32x4 v = buf[r % NPF];
            if (r + NPF < R3)
                buf[r % NPF] = __builtin_nontemporal_load(&vp[(size_t)(r + NPF) << 8]);
            ax = fmaf(w, v.x, ax);
            ay = fmaf(w, v.y, ay);
            az = fmaf(w, v.z, az);
            aw = fmaf(w, v.w, aw);
        }
        float* ms = macc + (size_t)slot * NHID;
        atomicAdd(&ms[4 * tid + 0], ax);
        atomicAdd(&ms[4 * tid + 1], ay);
        atomicAdd(&ms[4 * tid + 2], az);
        atomicAdd(&ms[4 * tid + 3], aw);
    } else {
        int wave = tid >> 6, lane = tid & 63;
        int row = (blockIdx.x - NB3) * 4 + wave;
        const f32x4* w4 = (const f32x4*)(Wh + (size_t)row * NHID);
        const f32x4* h4 = (const f32x4*)h;
        float p = 0.f;
#pragma unroll
        for (int j = 0; j < 4; ++j) {
            f32x4 wv = __builtin_nontemporal_load(&w4[j * 64 + lane]);
            f32x4 hv = h4[j * 64 + lane];
            p += wv.x * hv.x + wv.y * hv.y + wv.z * hv.z + wv.w * hv.w;
        }
        if (lane < NIN) p += x[lane] * Wi[(size_t)row * NIN + lane];
        p = wave_reduce_sum(p);
        if (lane == 0) preact[row] = p + bi[row] + bh[row];
    }
}

// Fused cell update + hidden GEMV. Every block redundantly computes the full
// 1024-wide cell update (L2-hot inputs), stashes h_t in LDS, then computes its
// 4 rows of hh = relu(W_ih . h_t + b_ih). Block 0 also writes h_t/c_t to out.
__global__ void __launch_bounds__(256) k45(const float* __restrict__ preact,
                                           const float* __restrict__ macc,
                                           const float* __restrict__ Lacc,
                                           const float* __restrict__ c_in,
                                           const float* __restrict__ Wih,
                                           const float* __restrict__ bih,
                                           float* __restrict__ out,
                                           float* __restrict__ hh) {
    __shared__ float hlds[NHID];
    int tid = threadIdx.x;
    float Ls = 0.f;
#pragma unroll
    for (int s = 0; s < NSLOT; ++s) Ls += Lacc[s];
    float invL = 1.0f / Ls;
    const f32x4* pre4 = (const f32x4*)preact;
    f32x4 fg = pre4[tid];
    f32x4 ig = pre4[256 + tid];
    f32x4 og = pre4[512 + tid];
    f32x4 rg = pre4[768 + tid];
    f32x4 gg = pre4[1024 + tid];
    f32x4 m4 = {0.f, 0.f, 0.f, 0.f};
#pragma unroll
    for (int s = 0; s < NSLOT; ++s) m4 += ((const f32x4*)(macc + (size_t)s * NHID))[tid];
    f32x4 c4 = ((const f32x4*)c_in)[tid];
    f32x4 h4, ct4;
#pragma unroll
    for (int e = 0; e < 4; ++e) {
        float f = sigm(fg[e]);
        float i = sigm(ig[e]);
        float o = sigm(og[e]);
        float r = sigm(rg[e]);
        float cn = tanhf(gg[e]);
        float mt = tanhf(m4[e] * invL);
        float ct = f * c4[e] + i * cn + r * mt;
        ct4[e] = ct;
        h4[e] = o * tanhf(ct);
    }
    ((f32x4*)hlds)[tid] = h4;
    if (blockIdx.x == 0) {
        ((f32x4*)(out + 4))[tid] = h4;
        ((f32x4*)(out + 4 + NHID))[tid] = ct4;
    }
    __syncthreads();
    int wave = tid >> 6, lane = tid & 63;
    int row = blockIdx.x * 4 + wave;
    const f32x4* w4 = (const f32x4*)(Wih + (size_t)row * NHID);
    const f32x4* hl4 = (const f32x4*)hlds;
    float p = 0.f;
#pragma unroll
    for (int j = 0; j < 4; ++j) {
        f32x4 wv = __builtin_nontemporal_load(&w4[j * 64 + lane]);
        f32x4 hv = hl4[j * 64 + lane];
        p += wv.x * hv.x + wv.y * hv.y + wv.z * hv.z + wv.w * hv.w;
    }
    p = wave_reduce_sum(p);
    if (lane == 0) hh[row] = fmaxf(p + bih[row], 0.f);
}

#define TF_ROUND(r) { x0 += x1; x1 = (x1 << r) | (x1 >> (32 - r)); x1 ^= x0; }

// actor/critic heads + jax.random.categorical(key(1), log pi) replication
__global__ void k6_heads(const float* __restrict__ hh, const float* __restrict__ Wa,
                         const float* __restrict__ ba, const float* __restrict__ Wc,
                         const float* __restrict__ bc, float* __restrict__ out) {
    __shared__ float zz[3];
    int wave = threadIdx.x >> 6, lane = threadIdx.x & 63;
    if (wave < 3) {
        const float* W = (wave == 2) ? Wc : Wa + wave * NHID;
        const f32x4* w4 = (const f32x4*)W;
        const f32x4* h4 = (const f32x4*)hh;
        float p = 0.f;
#pragma unroll
        for (int j = 0; j < 4; ++j) {
            f32x4 wv = w4[j * 64 + lane];
            f32x4 hv = h4[j * 64 + lane];
            p += wv.x * hv.x + wv.y * hv.y + wv.z * hv.z + wv.w * hv.w;
        }
        p = wave_reduce_sum(p);
        if (lane == 0) zz[wave] = p;
    }
    __syncthreads();
    if (threadIdx.x == 0) {
        float z0 = zz[0] + ba[0], z1 = zz[1] + ba[1], v = zz[2] + bc[0];
        float mz = fmaxf(z0, z1);
        float e0 = expf(z0 - mz), e1 = expf(z1 - mz);
        float sum = e0 + e1;
        float pi0 = e0 / sum, pi1 = e1 / sum;
        float lse = mz + logf(sum);
        // Threefry-2x32, key = (0,1) [jax.random.key(1)], counter = (0,1)
        unsigned ks0 = 0u, ks1 = 1u, ks2 = 0u ^ 1u ^ 0x1BD11BDAu;
        unsigned x0 = 0u + ks0, x1 = 1u + ks1;
        TF_ROUND(13) TF_ROUND(15) TF_ROUND(26) TF_ROUND(6)
        x0 += ks1; x1 += ks2 + 1u;
        TF_ROUND(17) TF_ROUND(29) TF_ROUND(16) TF_ROUND(24)
        x0 += ks2; x1 += ks0 + 2u;
        TF_ROUND(13) TF_ROUND(15) TF_ROUND(26) TF_ROUND(6)
        x0 += ks0; x1 += ks1 + 3u;
        TF_ROUND(17) TF_ROUND(29) TF_ROUND(16) TF_ROUND(24)
        x0 += ks1; x1 += ks2 + 4u;
        TF_ROUND(13) TF_ROUND(15) TF_ROUND(26) TF_ROUND(6)
        x0 += ks2; x1 += ks0 + 5u;
        float u0 = __uint_as_float((x0 >> 9) | 0x3F800000u) - 1.0f;
        float u1 = __uint_as_float((x1 >> 9) | 0x3F800000u) - 1.0f;
        const float tiny = 1.17549435e-38f;
        u0 = fmaxf(u0, tiny); u1 = fmaxf(u1, tiny);
        float g0 = -logf(-logf(u0));
        float g1 = -logf(-logf(u1));
        int a = (z1 + g1 > z0 + g0) ? 1 : 0;
        float logp = (a ? z1 : z0) - lse;
        out[0] = pi0; out[1] = pi1; out[2] = v; out[3] = logp;
    }
}

extern "C" void kernel_launch(void* const* d_in, const int* in_sizes, int n_in,
                              void* d_out, int out_size, void* d_ws, size_t ws_size,
                              hipStream_t stream) {
    const float* x      = (const float*)d_in[0];
    const float* h      = (const float*)d_in[1];
    const float* c      = (const float*)d_in[2];
    const float* keys   = (const float*)d_in[3];
    const float* vals   = (const float*)d_in[4];
    const float* Wi2h   = (const float*)d_in[5];
    const float* bi2h   = (const float*)d_in[6];
    const float* Wh2h   = (const float*)d_in[7];
    const float* bh2h   = (const float*)d_in[8];
    const float* Wih    = (const float*)d_in[9];
    const float* bih    = (const float*)d_in[10];
    const float* Wact   = (const float*)d_in[11];
    const float* bact   = (const float*)d_in[12];
    const float* Wcrit  = (const float*)d_in[13];
    const float* bcrit  = (const float*)d_in[14];
    const int*   pick   = (const int*)d_in[15];
    float* out = (float*)d_out;
    float* ws  = (float*)d_ws;

    (void)hipMemsetAsync(ws, 0, ZERO_BYTES, stream);
    kA<<<NB3 + NBPRE, 256, 0, stream>>>(keys, x, pick, vals,
                                        ws + WS_MACC, ws + WS_L,
                                        h, Wi2h, bi2h, Wh2h, bh2h, ws + WS_PREACT);
    k45<<<NHID / 4, 256, 0, stream>>>(ws + WS_PREACT, ws + WS_MACC, ws + WS_L,
                                      c, Wih, bih, out, ws + WS_HH);
    k6_heads<<<1, 256, 0, stream>>>(ws + WS_HH, Wact, bact, Wcrit, bcrit, out);
}